// Round 1
// baseline (373.452 us; speedup 1.0000x reference)
//
#include <hip/hip_runtime.h>

#define D 256

// ---------------------------------------------------------------- k_zero
__global__ void k_zero(float* __restrict__ deg, int* __restrict__ cnt, int N) {
    int i = blockIdx.x * blockDim.x + threadIdx.x;
    if (i < N) deg[i] = 1.0f;          // self-loop: deg = intra_in_degree + 1
    if (i < 4096) cnt[i] = 0;
}

// ---------------------------------------------------------------- k_edges
__global__ void k_edges(const int* __restrict__ ei, const int* __restrict__ cl,
                        float* __restrict__ deg, int* __restrict__ cnt, int E) {
    int e = blockIdx.x * blockDim.x + threadIdx.x;
    if (e >= E) return;
    int s = ei[e];
    int d = ei[E + e];
    int cs = cl[s], cd = cl[d];
    if (cs == cd) {
        atomicAdd(&deg[d], 1.0f);      // integer counts in float: exact
        atomicAdd(&cnt[cd], 1);
    }
}

// ---------------------------------------------------------------- k_init
// out[n] = X[n] / deg[n]   (self-loop contribution of B = A_hat * X)
__global__ void k_init(const float* __restrict__ X, const float* __restrict__ deg,
                       float* __restrict__ out, int N) {
    int i = blockIdx.x * blockDim.x + threadIdx.x;   // over N * (D/4) float4s
    int total = N * (D / 4);
    if (i >= total) return;
    int n = i / (D / 4);
    float inv = 1.0f / deg[n];
    float4 x = ((const float4*)X)[i];
    x.x *= inv; x.y *= inv; x.z *= inv; x.w *= inv;
    ((float4*)out)[i] = x;
}

// ---------------------------------------------------------------- k_scatter
// one wave per edge; intra edges add norm * X[src] into out[dst]
__global__ void k_scatter(const int* __restrict__ ei, const int* __restrict__ cl,
                          const float* __restrict__ deg, const float* __restrict__ X,
                          float* __restrict__ out, int E) {
    int w = (int)((blockIdx.x * (unsigned)blockDim.x + threadIdx.x) >> 6);
    int lane = threadIdx.x & 63;
    if (w >= E) return;
    int s = ei[w];
    int d = ei[E + w];
    if (cl[s] != cl[d]) return;                       // wave-uniform branch
    float norm = rsqrtf(deg[s]) * rsqrtf(deg[d]);
    float4 xv = *(const float4*)(X + (size_t)s * D + lane * 4);
    float* op = out + (size_t)d * D + lane * 4;
    atomicAdd(op + 0, norm * xv.x);
    atomicAdd(op + 1, norm * xv.y);
    atomicAdd(op + 2, norm * xv.z);
    atomicAdd(op + 3, norm * xv.w);
}

// ---------------------------------------------------------------- k_gemm
// in-place: out_rows = active ? B_rows @ W + bias : X_rows
// block = 256 threads, 32 rows; thread computes 8 rows x 4 cols
__global__ __launch_bounds__(256) void k_gemm(
        const float* __restrict__ W, const float* __restrict__ bias,
        const float* __restrict__ X, const int* __restrict__ cl,
        const int* __restrict__ cnt, float* __restrict__ out, int N) {
    __shared__ float Bs[32][D];                       // 32 KB
    int r0 = blockIdx.x * 32;
    int tid = threadIdx.x;

    // stage 32 rows of B (currently living in `out`) into LDS, coalesced
    #pragma unroll 4
    for (int i = 0; i < 32; ++i) {
        int r = r0 + i;
        Bs[i][tid] = (r < N) ? out[(size_t)r * D + tid] : 0.0f;
    }
    __syncthreads();

    int tn = tid & 63;          // column group (lane within wave)
    int tm = tid >> 6;          // wave id -> row group
    int col0 = tn * 4;
    int row0 = tm * 8;

    float acc[8][4];
    #pragma unroll
    for (int i = 0; i < 8; ++i)
        #pragma unroll
        for (int j = 0; j < 4; ++j) acc[i][j] = 0.0f;

    for (int k4 = 0; k4 < D; k4 += 4) {
        // W rows k4..k4+3, cols col0..col0+3 — coalesced 16B/lane from L2
        float4 w0 = *(const float4*)(W + (size_t)(k4 + 0) * D + col0);
        float4 w1 = *(const float4*)(W + (size_t)(k4 + 1) * D + col0);
        float4 w2 = *(const float4*)(W + (size_t)(k4 + 2) * D + col0);
        float4 w3 = *(const float4*)(W + (size_t)(k4 + 3) * D + col0);
        #pragma unroll
        for (int i = 0; i < 8; ++i) {
            float4 a = *(const float4*)(&Bs[row0 + i][k4]);  // LDS broadcast
            acc[i][0] = fmaf(a.x, w0.x, fmaf(a.y, w1.x, fmaf(a.z, w2.x, fmaf(a.w, w3.x, acc[i][0]))));
            acc[i][1] = fmaf(a.x, w0.y, fmaf(a.y, w1.y, fmaf(a.z, w2.y, fmaf(a.w, w3.y, acc[i][1]))));
            acc[i][2] = fmaf(a.x, w0.z, fmaf(a.y, w1.z, fmaf(a.z, w2.z, fmaf(a.w, w3.z, acc[i][2]))));
            acc[i][3] = fmaf(a.x, w0.w, fmaf(a.y, w1.w, fmaf(a.z, w2.w, fmaf(a.w, w3.w, acc[i][3]))));
        }
    }

    float4 bv = *(const float4*)(bias + col0);
    #pragma unroll
    for (int i = 0; i < 8; ++i) {
        int r = r0 + row0 + i;
        if (r >= N) continue;
        bool act = cnt[cl[r]] > 0;                    // wave-uniform per row
        float4 o;
        if (act) {
            o.x = acc[i][0] + bv.x;
            o.y = acc[i][1] + bv.y;
            o.z = acc[i][2] + bv.z;
            o.w = acc[i][3] + bv.w;
        } else {
            o = *(const float4*)(X + (size_t)r * D + col0);
        }
        *(float4*)(out + (size_t)r * D + col0) = o;
    }
}

// ---------------------------------------------------------------- launch
extern "C" void kernel_launch(void* const* d_in, const int* in_sizes, int n_in,
                              void* d_out, int out_size, void* d_ws, size_t ws_size,
                              hipStream_t stream) {
    const float* X    = (const float*)d_in[0];
    const float* W    = (const float*)d_in[1];
    const float* bias = (const float*)d_in[2];
    const int*   cl   = (const int*)d_in[3];
    const int*   ei   = (const int*)d_in[4];
    int N = in_sizes[3];
    int E = in_sizes[4] / 2;
    float* out = (float*)d_out;

    float* deg = (float*)d_ws;
    size_t deg_bytes = ((size_t)N * sizeof(float) + 255) & ~(size_t)255;
    int* cnt = (int*)((char*)d_ws + deg_bytes);

    int nz = (N > 4096) ? N : 4096;
    k_zero<<<(nz + 255) / 256, 256, 0, stream>>>(deg, cnt, N);
    k_edges<<<(E + 255) / 256, 256, 0, stream>>>(ei, cl, deg, cnt, E);
    k_init<<<(N * (D / 4) + 255) / 256, 256, 0, stream>>>(X, deg, out, N);
    k_scatter<<<(E + 3) / 4, 256, 0, stream>>>(ei, cl, deg, X, out, E);
    k_gemm<<<(N + 31) / 32, 256, 0, stream>>>(W, bias, X, cl, cnt, out, N);
}

// Round 2
// 247.849 us; speedup vs baseline: 1.5068x; 1.5068x over previous
//
#include <hip/hip_runtime.h>

#define D 256

typedef float f32x4 __attribute__((ext_vector_type(4)));
typedef _Float16 f16x8 __attribute__((ext_vector_type(8)));

// ---------------------------------------------------------------- k_zero
__global__ void k_zero(float* __restrict__ deg, int* __restrict__ cnt, int N) {
    int i = blockIdx.x * blockDim.x + threadIdx.x;
    if (i < N) deg[i] = 1.0f;          // self-loop: deg = intra_in_degree + 1
    if (i < 4096) cnt[i] = 0;
}

// ---------------------------------------------------------------- k_edges
__global__ void k_edges(const int* __restrict__ ei, const int* __restrict__ cl,
                        float* __restrict__ deg, int* __restrict__ cnt, int E) {
    int e = blockIdx.x * blockDim.x + threadIdx.x;
    if (e >= E) return;
    int s = ei[e];
    int d = ei[E + e];
    int cs = cl[s], cd = cl[d];
    if (cs == cd) {
        atomicAdd(&deg[d], 1.0f);      // integer counts in float: exact
        atomicAdd(&cnt[cd], 1);
    }
}

// ---------------------------------------------------------------- k_init
// Sparse: only rows with deg>1 get B_row = X_row / deg written to out.
// Rows with deg==1 keep B_row == X_row implicitly (GEMM reads X directly).
__global__ void k_init(const float* __restrict__ X, const float* __restrict__ deg,
                       float* __restrict__ out, int N) {
    int w = blockIdx.x * (blockDim.x >> 6) + (threadIdx.x >> 6);
    int lane = threadIdx.x & 63;
    if (w >= N) return;
    float dg = deg[w];
    if (dg <= 1.0f) return;            // untouched row: skip entirely
    float inv = 1.0f / dg;
    float4 x = *(const float4*)(X + (size_t)w * D + lane * 4);
    x.x *= inv; x.y *= inv; x.z *= inv; x.w *= inv;
    *(float4*)(out + (size_t)w * D + lane * 4) = x;
}

// ---------------------------------------------------------------- k_scatter
// thread-per-edge intra check; wave cooperatively processes surviving edges
__global__ void k_scatter(const int* __restrict__ ei, const int* __restrict__ cl,
                          const float* __restrict__ deg, const float* __restrict__ X,
                          float* __restrict__ out, int E) {
    int e = blockIdx.x * blockDim.x + threadIdx.x;
    int lane = threadIdx.x & 63;
    int s = 0, d = 0;
    bool intra = false;
    if (e < E) {
        s = ei[e];
        d = ei[E + e];
        intra = (cl[s] == cl[d]);
    }
    unsigned long long mask = __ballot(intra);
    while (mask) {
        int b = __ffsll((long long)mask) - 1;
        mask &= mask - 1;
        int ss = __shfl(s, b);
        int dd = __shfl(d, b);
        float norm = rsqrtf(deg[ss]) * rsqrtf(deg[dd]);
        float4 xv = *(const float4*)(X + (size_t)ss * D + lane * 4);
        float* op = out + (size_t)dd * D + lane * 4;
        atomicAdd(op + 0, norm * xv.x);
        atomicAdd(op + 1, norm * xv.y);
        atomicAdd(op + 2, norm * xv.z);
        atomicAdd(op + 3, norm * xv.w);
    }
}

// ---------------------------------------------------------------- k_prepw
// Pack W (f32 [k][n]) into per-fragment f16 layout:
//   frag(ct, ks): lane = h*16 + cn holds W[ks*32 + h*8 + i][ct*16 + cn], i=0..7
__global__ void k_prepw(const float* __restrict__ W, _Float16* __restrict__ Wp) {
    int idx = blockIdx.x * blockDim.x + threadIdx.x;
    if (idx >= D * D) return;
    int k = idx >> 8, n = idx & 255;
    int ks = k >> 5, kk = k & 31;
    int h = kk >> 3, i = kk & 7;
    int ct = n >> 4, cn = n & 15;
    int lane = h * 16 + cn;
    Wp[(((ct * 8 + ks) * 64 + lane) << 3) + i] = (_Float16)W[idx];
}

// ---------------------------------------------------------------- k_gemm
// out_rows = active ? B_rows @ W + bias : X_rows     (B read from out/X by deg)
// 4 waves/block, wave owns 32 rows x 256 cols. W frags from global (L1/L2-hot),
// A frags global->reg with f32->f16 cvt. No LDS, no barriers.
__global__ __launch_bounds__(256) void k_gemm(
        const _Float16* __restrict__ Wp, const float* __restrict__ bias,
        const float* __restrict__ X, const float* __restrict__ deg,
        const int* __restrict__ cl, const int* __restrict__ cnt,
        float* __restrict__ out, int N) {
    int lane = threadIdx.x & 63;
    int wid  = threadIdx.x >> 6;
    long row0 = (long)blockIdx.x * 128 + wid * 32;
    if (row0 >= N) return;
    int rA = lane & 15;   // row within 16-row tile (A operand)
    int h  = lane >> 4;   // k-subgroup
    long lastOwn = (row0 + 31 < (long)N - 1) ? row0 + 31 : (long)N - 1;

    // A source rows (clamped into this wave's own range -> no cross-wave race)
    const float* arow[2];
    #pragma unroll
    for (int rt = 0; rt < 2; ++rt) {
        long r = row0 + rt * 16 + rA;
        if (r > lastOwn) r = row0;
        const float* src = (deg[r] > 1.0f) ? out : X;
        arow[rt] = src + r * D;
    }

    f32x4 acc[2][16];
    #pragma unroll
    for (int rt = 0; rt < 2; ++rt)
        #pragma unroll
        for (int ct = 0; ct < 16; ++ct)
            acc[rt][ct] = (f32x4){0.f, 0.f, 0.f, 0.f};

    #pragma unroll
    for (int ks = 0; ks < 8; ++ks) {
        f16x8 wf[16];
        #pragma unroll
        for (int ct = 0; ct < 16; ++ct)
            wf[ct] = *(const f16x8*)(Wp + (((ct * 8 + ks) * 64 + lane) << 3));
        #pragma unroll
        for (int rt = 0; rt < 2; ++rt) {
            const float* ap = arow[rt] + ks * 32 + h * 8;
            float4 a0 = *(const float4*)(ap);
            float4 a1 = *(const float4*)(ap + 4);
            f16x8 af;
            af[0] = (_Float16)a0.x; af[1] = (_Float16)a0.y;
            af[2] = (_Float16)a0.z; af[3] = (_Float16)a0.w;
            af[4] = (_Float16)a1.x; af[5] = (_Float16)a1.y;
            af[6] = (_Float16)a1.z; af[7] = (_Float16)a1.w;
            #pragma unroll
            for (int ct = 0; ct < 16; ++ct)
                acc[rt][ct] = __builtin_amdgcn_mfma_f32_16x16x32_f16(
                                  af, wf[ct], acc[rt][ct], 0, 0, 0);
        }
    }

    // epilogue: D layout col = lane&15, row = h*4 + j
    int cn = lane & 15;
    float bv[16];
    #pragma unroll
    for (int ct = 0; ct < 16; ++ct) bv[ct] = bias[ct * 16 + cn];

    #pragma unroll
    for (int rt = 0; rt < 2; ++rt) {
        #pragma unroll
        for (int j = 0; j < 4; ++j) {
            long r = row0 + rt * 16 + h * 4 + j;
            if (r >= N) continue;
            bool act = cnt[cl[r]] > 0;
            float* orow = out + r * D;
            const float* xrow = X + r * D;
            #pragma unroll
            for (int ct = 0; ct < 16; ++ct) {
                float v = acc[rt][ct][j] + bv[ct];
                if (!act) v = xrow[ct * 16 + cn];
                orow[ct * 16 + cn] = v;
            }
        }
    }
}

// ---------------------------------------------------------------- launch
extern "C" void kernel_launch(void* const* d_in, const int* in_sizes, int n_in,
                              void* d_out, int out_size, void* d_ws, size_t ws_size,
                              hipStream_t stream) {
    const float* X    = (const float*)d_in[0];
    const float* W    = (const float*)d_in[1];
    const float* bias = (const float*)d_in[2];
    const int*   cl   = (const int*)d_in[3];
    const int*   ei   = (const int*)d_in[4];
    int N = in_sizes[3];
    int E = in_sizes[4] / 2;
    float* out = (float*)d_out;

    char* ws = (char*)d_ws;
    float* deg = (float*)ws;
    size_t off = ((size_t)N * sizeof(float) + 255) & ~(size_t)255;
    int* cnt = (int*)(ws + off);
    off += 4096 * sizeof(int);
    _Float16* Wp = (_Float16*)(ws + off);   // 128 KB packed W fragments

    int nz = (N > 4096) ? N : 4096;
    k_zero<<<(nz + 255) / 256, 256, 0, stream>>>(deg, cnt, N);
    k_prepw<<<(D * D + 255) / 256, 256, 0, stream>>>(W, Wp);
    k_edges<<<(E + 255) / 256, 256, 0, stream>>>(ei, cl, deg, cnt, E);
    k_init<<<(N + 3) / 4, 256, 0, stream>>>(X, deg, out, N);
    k_scatter<<<(E + 255) / 256, 256, 0, stream>>>(ei, cl, deg, X, out, E);
    k_gemm<<<(N + 127) / 128, 256, 0, stream>>>(Wp, bias, X, deg, cl, cnt, out, N);
}

// Round 3
// 246.887 us; speedup vs baseline: 1.5126x; 1.0039x over previous
//
#include <hip/hip_runtime.h>

#define D 256

typedef float f32x4 __attribute__((ext_vector_type(4)));
typedef _Float16 f16x8 __attribute__((ext_vector_type(8)));

// ---------------------------------------------------------------- k_edges
// degx[d] += 1 per intra edge (deg = degx + 1); cnt[c] = intra edges per cluster
__global__ void k_edges(const int* __restrict__ ei, const int* __restrict__ cl,
                        float* __restrict__ degx, int* __restrict__ cnt, int E) {
    int e = blockIdx.x * blockDim.x + threadIdx.x;
    if (e >= E) return;
    int s = ei[e];
    int d = ei[E + e];
    int cs = cl[s], cd = cl[d];
    if (cs == cd) {
        atomicAdd(&degx[d], 1.0f);     // integer counts in float: exact
        atomicAdd(&cnt[cd], 1);
    }
}

// ---------------------------------------------------------------- k_init
// rows with degx>0: out_row = X_row / (degx+1). Ballot-compacted.
__global__ void k_init(const float* __restrict__ X, const float* __restrict__ degx,
                       float* __restrict__ out, int N) {
    int i = blockIdx.x * blockDim.x + threadIdx.x;
    int lane = threadIdx.x & 63;
    float dx = 0.0f;
    bool hit = false;
    if (i < N) { dx = degx[i]; hit = dx > 0.0f; }
    unsigned long long m = __ballot(hit);
    int base = i - lane;
    while (m) {
        int b = __ffsll((long long)m) - 1;
        m &= m - 1;
        int r = base + b;
        float inv = 1.0f / (__shfl(dx, b) + 1.0f);
        float4 x = *(const float4*)(X + (size_t)r * D + lane * 4);
        x.x *= inv; x.y *= inv; x.z *= inv; x.w *= inv;
        *(float4*)(out + (size_t)r * D + lane * 4) = x;
    }
}

// ---------------------------------------------------------------- k_scatter
// thread-per-edge intra check; wave cooperatively processes surviving edges
__global__ void k_scatter(const int* __restrict__ ei, const int* __restrict__ cl,
                          const float* __restrict__ degx, const float* __restrict__ X,
                          float* __restrict__ out, int E) {
    int e = blockIdx.x * blockDim.x + threadIdx.x;
    int lane = threadIdx.x & 63;
    int s = 0, d = 0;
    bool intra = false;
    if (e < E) {
        s = ei[e];
        d = ei[E + e];
        intra = (cl[s] == cl[d]);
    }
    unsigned long long mask = __ballot(intra);
    while (mask) {
        int b = __ffsll((long long)mask) - 1;
        mask &= mask - 1;
        int ss = __shfl(s, b);
        int dd = __shfl(d, b);
        float norm = rsqrtf((degx[ss] + 1.0f) * (degx[dd] + 1.0f));
        float4 xv = *(const float4*)(X + (size_t)ss * D + lane * 4);
        float* op = out + (size_t)dd * D + lane * 4;
        atomicAdd(op + 0, norm * xv.x);
        atomicAdd(op + 1, norm * xv.y);
        atomicAdd(op + 2, norm * xv.z);
        atomicAdd(op + 3, norm * xv.w);
    }
}

// ---------------------------------------------------------------- k_prepw
// Pack W (f32 [k][n]) into per-fragment f16 layout:
//   frag(ct, ks): lane = h*16 + cn holds W[ks*32 + h*8 + i][ct*16 + cn], i=0..7
__global__ void k_prepw(const float* __restrict__ W, _Float16* __restrict__ Wp) {
    int idx = blockIdx.x * blockDim.x + threadIdx.x;
    if (idx >= D * D) return;
    int k = idx >> 8, n = idx & 255;
    int ks = k >> 5, kk = k & 31;
    int h = kk >> 3, i = kk & 7;
    int ct = n >> 4, cn = n & 15;
    int lane = h * 16 + cn;
    Wp[(((ct * 8 + ks) * 64 + lane) << 3) + i] = (_Float16)W[idx];
}

// ---------------------------------------------------------------- k_gemm
// wave owns 16 rows x 256 cols; acc[16] = 64 VGPRs; wf live range = 1 iter.
// 4 waves/block, __launch_bounds__(256,4) -> 4 waves/SIMD target.
__global__ __launch_bounds__(256, 4) void k_gemm(
        const _Float16* __restrict__ Wp, const float* __restrict__ bias,
        const float* __restrict__ X, const float* __restrict__ degx,
        const int* __restrict__ cl, const int* __restrict__ cnt,
        float* __restrict__ out, int N) {
    int lane = threadIdx.x & 63;
    int wid  = threadIdx.x >> 6;
    long row0 = (long)blockIdx.x * 64 + wid * 16;
    if (row0 >= N) return;
    int rA = lane & 15;   // A row within the 16-row tile
    int h  = lane >> 4;   // k-subgroup

    long r = row0 + rA;
    long lastOwn = (row0 + 15 < (long)N - 1) ? row0 + 15 : (long)N - 1;
    if (r > lastOwn) r = row0;                 // clamp within own rows: no race
    const float* arow = ((degx[r] > 0.0f) ? out : X) + r * D;

    f32x4 acc[16];
    #pragma unroll
    for (int ct = 0; ct < 16; ++ct) acc[ct] = (f32x4){0.f, 0.f, 0.f, 0.f};

    #pragma unroll
    for (int ks = 0; ks < 8; ++ks) {
        const float* ap = arow + ks * 32 + h * 8;
        float4 a0 = *(const float4*)(ap);
        float4 a1 = *(const float4*)(ap + 4);
        f16x8 af;
        af[0] = (_Float16)a0.x; af[1] = (_Float16)a0.y;
        af[2] = (_Float16)a0.z; af[3] = (_Float16)a0.w;
        af[4] = (_Float16)a1.x; af[5] = (_Float16)a1.y;
        af[6] = (_Float16)a1.z; af[7] = (_Float16)a1.w;
        #pragma unroll
        for (int ct = 0; ct < 16; ++ct) {
            f16x8 wf = *(const f16x8*)(Wp + (((ct * 8 + ks) * 64 + lane) << 3));
            acc[ct] = __builtin_amdgcn_mfma_f32_16x16x32_f16(af, wf, acc[ct], 0, 0, 0);
        }
    }

    // epilogue: D layout col = ct*16 + (lane&15), row = h*4 + j
    int cn = lane & 15;
    #pragma unroll
    for (int j = 0; j < 4; ++j) {
        long rr = row0 + h * 4 + j;
        if (rr >= N) continue;
        bool act = cnt[cl[rr]] > 0;
        float* orow = out + rr * D;
        const float* xrow = X + rr * D;
        #pragma unroll
        for (int ct = 0; ct < 16; ++ct) {
            float v = acc[ct][j] + bias[ct * 16 + cn];
            if (!act) v = xrow[ct * 16 + cn];
            orow[ct * 16 + cn] = v;
        }
    }
}

// ---------------------------------------------------------------- launch
extern "C" void kernel_launch(void* const* d_in, const int* in_sizes, int n_in,
                              void* d_out, int out_size, void* d_ws, size_t ws_size,
                              hipStream_t stream) {
    const float* X    = (const float*)d_in[0];
    const float* W    = (const float*)d_in[1];
    const float* bias = (const float*)d_in[2];
    const int*   cl   = (const int*)d_in[3];
    const int*   ei   = (const int*)d_in[4];
    int N = in_sizes[3];
    int E = in_sizes[4] / 2;
    float* out = (float*)d_out;

    char* ws = (char*)d_ws;
    float* degx = (float*)ws;                                  // N floats, zeroed
    size_t off = ((size_t)N * sizeof(float) + 255) & ~(size_t)255;
    int* cnt = (int*)(ws + off);                               // 4096 ints, zeroed
    size_t zbytes = off + 4096 * sizeof(int);
    _Float16* Wp = (_Float16*)(ws + ((zbytes + 255) & ~(size_t)255));  // 128 KB

    hipMemsetAsync(ws, 0, zbytes, stream);
    k_prepw<<<(D * D + 255) / 256, 256, 0, stream>>>(W, Wp);
    k_edges<<<(E + 255) / 256, 256, 0, stream>>>(ei, cl, degx, cnt, E);
    k_init<<<(N + 255) / 256, 256, 0, stream>>>(X, degx, out, N);
    k_scatter<<<(E + 255) / 256, 256, 0, stream>>>(ei, cl, degx, X, out, E);
    k_gemm<<<(N + 63) / 64, 256, 0, stream>>>(Wp, bias, X, degx, cl, cnt, out, N);
}

// Round 5
// 208.315 us; speedup vs baseline: 1.7927x; 1.1852x over previous
//
#include <hip/hip_runtime.h>

#define D 256

typedef float f32x4 __attribute__((ext_vector_type(4)));
typedef _Float16 f16x8 __attribute__((ext_vector_type(8)));

// ---------------------------------------------------------------- k_edges
__global__ void k_edges(const int* __restrict__ ei, const int* __restrict__ cl,
                        float* __restrict__ degx, int* __restrict__ cnt, int E) {
    int e = blockIdx.x * blockDim.x + threadIdx.x;
    if (e >= E) return;
    int s = ei[e];
    int d = ei[E + e];
    int cs = cl[s], cd = cl[d];
    if (cs == cd) {
        unsafeAtomicAdd(&degx[d], 1.0f);   // HW global_atomic_add_f32, exact ints
        atomicAdd(&cnt[cd], 1);
    }
}

// ---------------------------------------------------------------- k_init
// rows with degx>0: out_row = X_row / (degx+1). Ballot-compacted.
__global__ void k_init(const float* __restrict__ X, const float* __restrict__ degx,
                       float* __restrict__ out, int N) {
    int i = blockIdx.x * blockDim.x + threadIdx.x;
    int lane = threadIdx.x & 63;
    float dx = 0.0f;
    bool hit = false;
    if (i < N) { dx = degx[i]; hit = dx > 0.0f; }
    unsigned long long m = __ballot(hit);
    int base = i - lane;
    while (m) {
        int b = __ffsll((long long)m) - 1;
        m &= m - 1;
        int r = base + b;
        float inv = 1.0f / (__shfl(dx, b) + 1.0f);
        float4 x = *(const float4*)(X + (size_t)r * D + lane * 4);
        x.x *= inv; x.y *= inv; x.z *= inv; x.w *= inv;
        *(float4*)(out + (size_t)r * D + lane * 4) = x;
    }
}

// ---------------------------------------------------------------- k_scatter
__global__ void k_scatter(const int* __restrict__ ei, const int* __restrict__ cl,
                          const float* __restrict__ degx, const float* __restrict__ X,
                          float* __restrict__ out, int E) {
    int e = blockIdx.x * blockDim.x + threadIdx.x;
    int lane = threadIdx.x & 63;
    int s = 0, d = 0;
    bool intra = false;
    if (e < E) {
        s = ei[e];
        d = ei[E + e];
        intra = (cl[s] == cl[d]);
    }
    unsigned long long mask = __ballot(intra);
    while (mask) {
        int b = __ffsll((long long)mask) - 1;
        mask &= mask - 1;
        int ss = __shfl(s, b);
        int dd = __shfl(d, b);
        float norm = rsqrtf((degx[ss] + 1.0f) * (degx[dd] + 1.0f));
        float4 xv = *(const float4*)(X + (size_t)ss * D + lane * 4);
        float* op = out + (size_t)dd * D + lane * 4;
        unsafeAtomicAdd(op + 0, norm * xv.x);
        unsafeAtomicAdd(op + 1, norm * xv.y);
        unsafeAtomicAdd(op + 2, norm * xv.z);
        unsafeAtomicAdd(op + 3, norm * xv.w);
    }
}

// ---------------------------------------------------------------- k_prepw
// Pack W (f32 [k][n]) into K-major f16 fragment layout:
//   Wp[(((ks*16 + ct)*64 + lane) * 8) + i] = W[ks*32 + h*8 + i][ct*16 + cn]
// where lane = h*16 + cn. Each K-quarter (2 ks values) is a contiguous 32 KB.
__global__ void k_prepw(const float* __restrict__ W, _Float16* __restrict__ Wp) {
    int idx = blockIdx.x * blockDim.x + threadIdx.x;
    if (idx >= D * D) return;
    int k = idx >> 8, n = idx & 255;
    int ks = k >> 5, kk = k & 31;
    int h = kk >> 3, i = kk & 7;
    int ct = n >> 4, cn = n & 15;
    int lane = h * 16 + cn;
    Wp[(((ks * 16 + ct) * 64 + lane) << 3) + i] = (_Float16)W[idx];
}

// ---------------------------------------------------------------- k_gemm
// Block = 4 waves x 16 rows = 64 rows, full 256 cols.
// W staged K-quarter at a time (32 KB LDS) via global_load_lds width=16;
// A-loads pipelined one quarter ahead (drain with the stage's vmcnt(0)).
// A fragment: lane (h*16+rA) of row-tile holds arow[k = ks*32 + h*8 + i].
__global__ __launch_bounds__(256) void k_gemm(
        const _Float16* __restrict__ Wp, const float* __restrict__ bias,
        const float* __restrict__ X, const float* __restrict__ degx,
        const int* __restrict__ cl, const int* __restrict__ cnt,
        float* __restrict__ out, int N) {
    __shared__ _Float16 Wl[16384];             // 32 KB: one K-quarter
    int tid  = threadIdx.x;
    int lane = tid & 63;
    int wid  = tid >> 6;
    long row0 = (long)blockIdx.x * 64 + wid * 16;
    int rA = lane & 15;   // A row within 16-row tile
    int h  = lane >> 4;   // k-subgroup

    long r = row0 + rA;
    if (r > (long)N - 1) r = (long)N - 1;      // clamp: read-only, stores guarded
    const float* arow = ((degx[r] > 0.0f) ? out : X) + r * D;

    f32x4 acc[16];
    #pragma unroll
    for (int ct = 0; ct < 16; ++ct) acc[ct] = (f32x4){0.f, 0.f, 0.f, 0.f};

    // preload A quarter 0: k = 0*64 + ksl*32 + h*8 + {0..7}
    const float* ap0 = arow + h * 8;
    float4 a0c = *(const float4*)(ap0 + 0);
    float4 a1c = *(const float4*)(ap0 + 4);
    float4 a2c = *(const float4*)(ap0 + 32);
    float4 a3c = *(const float4*)(ap0 + 36);

    #pragma unroll
    for (int q = 0; q < 4; ++q) {
        __syncthreads();                       // previous compute done with Wl
        // stage quarter q: 32 KB, 8 iters x (4 waves x 1 KB)
        const char* src = (const char*)Wp + q * 32768 + wid * 1024 + lane * 16;
        #pragma unroll
        for (int it = 0; it < 8; ++it) {
            __builtin_amdgcn_global_load_lds(
                (const __attribute__((address_space(1))) void*)(src + it * 4096),
                (__attribute__((address_space(3))) void*)((char*)Wl + wid * 1024 + it * 4096),
                16, 0, 0);
        }
        // issue next quarter's A loads BEFORE the barrier (overlap with stage)
        float4 a0n = a0c, a1n = a1c, a2n = a2c, a3n = a3c;
        if (q < 3) {
            const float* apn = arow + (q + 1) * 64 + h * 8;
            a0n = *(const float4*)(apn + 0);
            a1n = *(const float4*)(apn + 4);
            a2n = *(const float4*)(apn + 32);
            a3n = *(const float4*)(apn + 36);
        }
        __syncthreads();                       // vmcnt(0): stage + A complete

        #pragma unroll
        for (int ksl = 0; ksl < 2; ++ksl) {
            float4 a0 = ksl ? a2c : a0c;
            float4 a1 = ksl ? a3c : a1c;
            f16x8 af;
            af[0] = (_Float16)a0.x; af[1] = (_Float16)a0.y;
            af[2] = (_Float16)a0.z; af[3] = (_Float16)a0.w;
            af[4] = (_Float16)a1.x; af[5] = (_Float16)a1.y;
            af[6] = (_Float16)a1.z; af[7] = (_Float16)a1.w;
            #pragma unroll
            for (int ct = 0; ct < 16; ++ct) {
                f16x8 wf = *(const f16x8*)&Wl[(((ksl * 16 + ct) * 64) + lane) << 3];
                acc[ct] = __builtin_amdgcn_mfma_f32_16x16x32_f16(af, wf, acc[ct], 0, 0, 0);
            }
        }
        a0c = a0n; a1c = a1n; a2c = a2n; a3c = a3n;
    }

    // epilogue: D layout col = ct*16 + (lane&15), row = h*4 + j
    int cn = lane & 15;
    #pragma unroll
    for (int j = 0; j < 4; ++j) {
        long rr = row0 + h * 4 + j;
        if (rr >= N) continue;
        bool act = cnt[cl[rr]] > 0;
        float* orow = out + rr * D;
        const float* xrow = X + rr * D;
        #pragma unroll
        for (int ct = 0; ct < 16; ++ct) {
            float v = acc[ct][j] + bias[ct * 16 + cn];
            if (!act) v = xrow[ct * 16 + cn];
            orow[ct * 16 + cn] = v;
        }
    }
}

// ---------------------------------------------------------------- launch
extern "C" void kernel_launch(void* const* d_in, const int* in_sizes, int n_in,
                              void* d_out, int out_size, void* d_ws, size_t ws_size,
                              hipStream_t stream) {
    const float* X    = (const float*)d_in[0];
    const float* W    = (const float*)d_in[1];
    const float* bias = (const float*)d_in[2];
    const int*   cl   = (const int*)d_in[3];
    const int*   ei   = (const int*)d_in[4];
    int N = in_sizes[3];
    int E = in_sizes[4] / 2;
    float* out = (float*)d_out;

    char* ws = (char*)d_ws;
    float* degx = (float*)ws;                                  // N floats, zeroed
    size_t off = ((size_t)N * sizeof(float) + 255) & ~(size_t)255;
    int* cnt = (int*)(ws + off);                               // 4096 ints, zeroed
    size_t zbytes = off + 4096 * sizeof(int);
    _Float16* Wp = (_Float16*)(ws + ((zbytes + 255) & ~(size_t)255));  // 128 KB

    hipMemsetAsync(ws, 0, zbytes, stream);
    k_prepw<<<(D * D + 255) / 256, 256, 0, stream>>>(W, Wp);
    k_edges<<<(E + 255) / 256, 256, 0, stream>>>(ei, cl, degx, cnt, E);
    k_init<<<(N + 255) / 256, 256, 0, stream>>>(X, degx, out, N);
    k_scatter<<<(E + 255) / 256, 256, 0, stream>>>(ei, cl, degx, X, out, E);
    k_gemm<<<(N + 63) / 64, 256, 0, stream>>>(Wp, bias, X, degx, cl, cnt, out, N);
}